// Round 6
// baseline (928.150 us; speedup 1.0000x reference)
//
#include <hip/hip_runtime.h>

typedef __bf16 bf16;
typedef __bf16 bf16x8 __attribute__((ext_vector_type(8)));
typedef float floatx4 __attribute__((ext_vector_type(4)));

__device__ __forceinline__ floatx4 mfma16(bf16x8 a, bf16x8 b, floatx4 c) {
    return __builtin_amdgcn_mfma_f32_16x16x32_bf16(a, b, c, 0, 0, 0);
}

__device__ __forceinline__ void load16_lds(const void* g, void* l) {
    __builtin_amdgcn_global_load_lds(
        (const __attribute__((address_space(1))) void*)g,
        (__attribute__((address_space(3))) void*)(unsigned int)(unsigned long long)l,
        16, 0, 0);
}

// ---------------------------------------------------------------------------
// Dtype detector: fp32 buffers viewed as bf16 show wild exponents -> flag=1.
// ---------------------------------------------------------------------------
__global__ __launch_bounds__(256) void detect_dtype(const bf16* __restrict__ p,
                                                    int* __restrict__ flag) {
    __shared__ int bad;
    if (threadIdx.x == 0) bad = 0;
    __syncthreads();
    int lbad = 0;
    for (int i = threadIdx.x; i < 4096; i += 256) {
        const float v = (float)p[i];
        if (!isfinite(v) || fabsf(v) > 1e10f) lbad = 1;
    }
    if (lbad) atomicOr(&bad, 1);
    __syncthreads();
    if (threadIdx.x == 0) *flag = bad;
}

// ---------------------------------------------------------------------------
// Small vectors -> bf16 arena. bpr@0 bep@1024 fb1@2048(4096) fb2@6144
// l1g@7168 l1b@8192 l2g@9216 l2b@10240 l3g@11264 l3b@12288. 13312 total.
// ---------------------------------------------------------------------------
__global__ __launch_bounds__(256) void convert_vecs(
    const void* bpr, const void* bep, const void* fb1, const void* fb2,
    const void* g1, const void* b1, const void* g2, const void* b2,
    const void* g3, const void* b3, bf16* __restrict__ out,
    const int* __restrict__ flagp) {
    const int fl = *flagp;
    const int idx = blockIdx.x * 256 + threadIdx.x;
    const void* src;
    int off;
    if (idx < 1024)      { src = bpr; off = idx; }
    else if (idx < 2048) { src = bep; off = idx - 1024; }
    else if (idx < 6144) { src = fb1; off = idx - 2048; }
    else if (idx < 7168) { src = fb2; off = idx - 6144; }
    else {
        const void* t[6] = {g1, b1, g2, b2, g3, b3};
        src = t[(idx - 7168) >> 10];
        off = idx & 1023;
    }
    out[idx] = fl ? (bf16)((const float*)src)[off] : ((const bf16*)src)[off];
}

// ---------------------------------------------------------------------------
// resf_init: resf[i] = dyn(tgt[i]) + bias[col]   (4 elems/thread)
// ---------------------------------------------------------------------------
__global__ __launch_bounds__(256) void resf_init(const void* __restrict__ X,
                                                 const bf16* __restrict__ bias,
                                                 float* __restrict__ resf,
                                                 const int* __restrict__ flagp) {
    const int fl = *flagp;
    const size_t i0 = ((size_t)blockIdx.x * 256 + threadIdx.x) * 4;
    const int col = (int)(i0 & 1023);
#pragma unroll
    for (int e = 0; e < 4; e++) {
        const float xv = fl ? ((const float*)X)[i0 + e]
                            : (float)((const bf16*)X)[i0 + e];
        resf[i0 + e] = xv + (float)bias[col + e];
    }
}

// ---------------------------------------------------------------------------
// out_final: d_out[i] = resf[i] + fb2[col]  (dtype per flag), 4 elems/thread
// ---------------------------------------------------------------------------
__global__ __launch_bounds__(256) void out_final(const float* __restrict__ resf,
                                                 const bf16* __restrict__ bias,
                                                 void* __restrict__ out,
                                                 const int* __restrict__ flagp) {
    const int fl = *flagp;
    const size_t i0 = ((size_t)blockIdx.x * 256 + threadIdx.x) * 4;
    const int col = (int)(i0 & 1023);
#pragma unroll
    for (int e = 0; e < 4; e++) {
        const float v = resf[i0 + e] + (float)bias[col + e];
        if (fl) ((float*)out)[i0 + e] = v;
        else ((bf16*)out)[i0 + e] = (bf16)v;
    }
}

// ---------------------------------------------------------------------------
// LayerNorm, fp32 input (for resf).
// ---------------------------------------------------------------------------
__global__ __launch_bounds__(256) void ln_f32(const float* __restrict__ X,
                                              const bf16* __restrict__ G,
                                              const bf16* __restrict__ Bv,
                                              bf16* __restrict__ Y) {
    const int row = blockIdx.x;
    const int tid = threadIdx.x;
    const float* x = X + (size_t)row * 1024 + tid * 4;
    float v[4];
#pragma unroll
    for (int i = 0; i < 4; i++) v[i] = x[i];
    float s = v[0] + v[1] + v[2] + v[3];
    float q = v[0] * v[0] + v[1] * v[1] + v[2] * v[2] + v[3] * v[3];
#pragma unroll
    for (int off = 32; off >= 1; off >>= 1) {
        s += __shfl_xor(s, off);
        q += __shfl_xor(q, off);
    }
    __shared__ float ss[4], qq[4];
    const int wave = tid >> 6, lane = tid & 63;
    if (lane == 0) { ss[wave] = s; qq[wave] = q; }
    __syncthreads();
    s = ss[0] + ss[1] + ss[2] + ss[3];
    q = qq[0] + qq[1] + qq[2] + qq[3];
    const float mu = s * (1.0f / 1024.0f);
    const float var = q * (1.0f / 1024.0f) - mu * mu;
    const float rs = rsqrtf(var + 1e-5f);
    bf16* y = Y + (size_t)row * 1024 + tid * 4;
    const bf16* g = G + tid * 4;
    const bf16* b = Bv + tid * 4;
#pragma unroll
    for (int i = 0; i < 4; i++)
        y[i] = (bf16)((v[i] - mu) * rs * (float)g[i] + (float)b[i]);
}

// ---------------------------------------------------------------------------
// LayerNorm, raw input with device-side dtype dispatch (fp32/bf16 per flag).
// ---------------------------------------------------------------------------
__global__ __launch_bounds__(256) void ln_dyn(const void* __restrict__ X,
                                              const bf16* __restrict__ G,
                                              const bf16* __restrict__ Bv,
                                              bf16* __restrict__ Y,
                                              const int* __restrict__ flagp) {
    const int fl = *flagp;
    const int row = blockIdx.x;
    const int tid = threadIdx.x;
    float v[4];
    if (fl) {
        const float* x = (const float*)X + (size_t)row * 1024 + tid * 4;
#pragma unroll
        for (int i = 0; i < 4; i++) v[i] = x[i];
    } else {
        const bf16* x = (const bf16*)X + (size_t)row * 1024 + tid * 4;
#pragma unroll
        for (int i = 0; i < 4; i++) v[i] = (float)x[i];
    }
    float s = v[0] + v[1] + v[2] + v[3];
    float q = v[0] * v[0] + v[1] * v[1] + v[2] * v[2] + v[3] * v[3];
#pragma unroll
    for (int off = 32; off >= 1; off >>= 1) {
        s += __shfl_xor(s, off);
        q += __shfl_xor(q, off);
    }
    __shared__ float ss[4], qq[4];
    const int wave = tid >> 6, lane = tid & 63;
    if (lane == 0) { ss[wave] = s; qq[wave] = q; }
    __syncthreads();
    s = ss[0] + ss[1] + ss[2] + ss[3];
    q = qq[0] + qq[1] + qq[2] + qq[3];
    const float mu = s * (1.0f / 1024.0f);
    const float var = q * (1.0f / 1024.0f) - mu * mu;
    const float rs = rsqrtf(var + 1e-5f);
    bf16* y = Y + (size_t)row * 1024 + tid * 4;
    const bf16* g = G + tid * 4;
    const bf16* b = Bv + tid * 4;
#pragma unroll
    for (int i = 0; i < 4; i++)
        y[i] = (bf16)((v[i] - mu) * rs * (float)g[i] + (float)b[i]);
}

// ---------------------------------------------------------------------------
// One-shot transpose+convert of ALL 7 weights into the W_T arena.
// ---------------------------------------------------------------------------
__global__ __launch_bounds__(256) void transpose_all(
    const void* w0, const void* w1, const void* w2, const void* w3,
    const void* w4, const void* w5, const void* w6,
    bf16* __restrict__ out_base, const int* __restrict__ flagp) {
    const int fl = *flagp;
    const int cum[8] = {0, 3072, 4096, 6144, 7168, 8192, 12288, 16384};
    const int ntv[7] = {96, 32, 64, 32, 32, 128, 32};
    const int ldi[7] = {3072, 1024, 2048, 1024, 1024, 4096, 1024};
    const int ldo[7] = {1024, 1024, 1024, 1024, 1024, 1024, 4096};
    const size_t ooff[7] = {0, 3145728, 4194304, 6291456, 7340032, 8388608, 12582912};
    const void* ws[7] = {w0, w1, w2, w3, w4, w5, w6};

    const int g = blockIdx.x;
    int w = 0;
#pragma unroll
    for (int i = 1; i < 7; i++) if (g >= cum[i]) w = i;
    const int t = g - cum[w];
    const int xt = t % ntv[w], yt = t / ntv[w];
    const int n0 = xt * 32, k0 = yt * 32;
    const void* in = ws[w];
    bf16* out = out_base + ooff[w];
    const int ldin = ldi[w], ldout = ldo[w];

    __shared__ bf16 tile[32][33];
    const int x = threadIdx.x, y = threadIdx.y;
#pragma unroll
    for (int i = 0; i < 4; i++) {
        const size_t idx = (size_t)(k0 + y + 8 * i) * ldin + n0 + x;
        tile[y + 8 * i][x] = fl ? (bf16)((const float*)in)[idx]
                                : ((const bf16*)in)[idx];
    }
    __syncthreads();
#pragma unroll
    for (int i = 0; i < 4; i++)
        out[(size_t)(n0 + y + 8 * i) * ldout + k0 + x] = tile[x][y + 8 * i];
}

// ---------------------------------------------------------------------------
// GEMM (direct-store): C[M,N] = A @ B^T'. 128x128 tile, BK=32, async staging,
// XCD swizzle (yb = g%56). Epilogue variants as before.
// ---------------------------------------------------------------------------
__global__ __launch_bounds__(256) void gemm_bt(
    const bf16* __restrict__ A, int lda,
    const bf16* __restrict__ Bt, int ldb,
    const bf16* __restrict__ bias,
    const void* resd,
    const float* resf,
    bf16* outb, float* outf, void* dual,
    const int* __restrict__ flagp,
    int M, int N, int K, int relu) {
    __shared__ bf16 As[128 * 32];
    __shared__ bf16 Bs[128 * 32];
    const int fl = *flagp;
    const int tid = threadIdx.x;
    const int wave = tid >> 6, lane = tid & 63;
    const int quad = lane >> 4, l16 = lane & 15;
    const int g = blockIdx.x;
    const int yb = g % 56, xb = g / 56;
    const int m0 = yb * 128, n0 = xb * 128;
    const int wm = (wave >> 1) * 64, wn = (wave & 1) * 64;
    const int srow = tid >> 2, scol = (tid & 3) * 8;

    floatx4 acc[4][4] = {};

    const bf16* gA = A + (size_t)(m0 + srow) * lda + scol;
    const bf16* gB = Bt + (size_t)(n0 + srow) * ldb + scol;
    const size_t a64 = (size_t)64 * lda, b64 = (size_t)64 * ldb;

    for (int k0 = 0; k0 < K; k0 += 32) {
        load16_lds(gA + k0, &As[tid * 8]);
        load16_lds(gA + k0 + a64, &As[(tid + 256) * 8]);
        load16_lds(gB + k0, &Bs[tid * 8]);
        load16_lds(gB + k0 + b64, &Bs[(tid + 256) * 8]);
        __syncthreads();
        bf16x8 af[4], bfr[4];
#pragma unroll
        for (int i = 0; i < 4; i++)
            af[i] = *(const bf16x8*)(&As[(wm + i * 16 + l16) * 32 + quad * 8]);
#pragma unroll
        for (int j = 0; j < 4; j++)
            bfr[j] = *(const bf16x8*)(&Bs[(wn + j * 16 + l16) * 32 + quad * 8]);
#pragma unroll
        for (int i = 0; i < 4; i++)
#pragma unroll
            for (int j = 0; j < 4; j++)
                acc[i][j] = mfma16(af[i], bfr[j], acc[i][j]);
        __syncthreads();
    }

#pragma unroll
    for (int i = 0; i < 4; i++) {
        const int mbase = m0 + wm + i * 16 + quad * 4;
#pragma unroll
        for (int j = 0; j < 4; j++) {
            const int n = n0 + wn + j * 16 + l16;
            const float bv = bias ? (float)bias[n] : 0.0f;
#pragma unroll
            for (int r = 0; r < 4; r++) {
                const size_t idx = (size_t)(mbase + r) * N + n;
                float v = acc[i][j][r] + bv;
                if (relu && v < 0.0f) v = 0.0f;
                if (resd) v += fl ? ((const float*)resd)[idx]
                                  : (float)((const bf16*)resd)[idx];
                if (resf) v += resf[idx];
                if (dual) {
                    if (fl) ((float*)dual)[idx] = v;
                    else ((bf16*)dual)[idx] = (bf16)v;
                } else if (outf) {
                    outf[idx] = v;
                } else {
                    outb[idx] = (bf16)v;
                }
            }
        }
    }
}

// ---------------------------------------------------------------------------
// Split-K GEMM: partials atomically accumulated into accf (fp32).
// Grid = nsplit * (N/128) * 56. split = g / (nbx*56); inner keeps the XCD
// swizzle. Split 0 also adds bias (if given). accf must be pre-initialized.
// ---------------------------------------------------------------------------
__global__ __launch_bounds__(256) void gemm_splitk(
    const bf16* __restrict__ A, int lda,
    const bf16* __restrict__ Bt, int ldb,
    const bf16* __restrict__ bias,
    float* accf,
    int M, int N, int Ksplit) {
    __shared__ bf16 As[128 * 32];
    __shared__ bf16 Bs[128 * 32];
    const int tid = threadIdx.x;
    const int wave = tid >> 6, lane = tid & 63;
    const int quad = lane >> 4, l16 = lane & 15;
    const int nbx = N >> 7;
    const int per = nbx * 56;
    const int g = blockIdx.x;
    const int split = g / per;
    const int inner = g - split * per;
    const int yb = inner % 56, xb = inner / 56;
    const int m0 = yb * 128, n0 = xb * 128;
    const int wm = (wave >> 1) * 64, wn = (wave & 1) * 64;
    const int srow = tid >> 2, scol = (tid & 3) * 8;
    const int kbase = split * Ksplit;

    floatx4 acc[4][4] = {};

    const bf16* gA = A + (size_t)(m0 + srow) * lda + kbase + scol;
    const bf16* gB = Bt + (size_t)(n0 + srow) * ldb + kbase + scol;
    const size_t a64 = (size_t)64 * lda, b64 = (size_t)64 * ldb;

    for (int k0 = 0; k0 < Ksplit; k0 += 32) {
        load16_lds(gA + k0, &As[tid * 8]);
        load16_lds(gA + k0 + a64, &As[(tid + 256) * 8]);
        load16_lds(gB + k0, &Bs[tid * 8]);
        load16_lds(gB + k0 + b64, &Bs[(tid + 256) * 8]);
        __syncthreads();
        bf16x8 af[4], bfr[4];
#pragma unroll
        for (int i = 0; i < 4; i++)
            af[i] = *(const bf16x8*)(&As[(wm + i * 16 + l16) * 32 + quad * 8]);
#pragma unroll
        for (int j = 0; j < 4; j++)
            bfr[j] = *(const bf16x8*)(&Bs[(wn + j * 16 + l16) * 32 + quad * 8]);
#pragma unroll
        for (int i = 0; i < 4; i++)
#pragma unroll
            for (int j = 0; j < 4; j++)
                acc[i][j] = mfma16(af[i], bfr[j], acc[i][j]);
        __syncthreads();
    }

    const bf16* bb = (split == 0) ? bias : nullptr;
#pragma unroll
    for (int i = 0; i < 4; i++) {
        const int mbase = m0 + wm + i * 16 + quad * 4;
#pragma unroll
        for (int j = 0; j < 4; j++) {
            const int n = n0 + wn + j * 16 + l16;
            const float bv = bb ? (float)bb[n] : 0.0f;
#pragma unroll
            for (int r = 0; r < 4; r++) {
                const size_t idx = (size_t)(mbase + r) * N + n;
                atomicAdd(&accf[idx], acc[i][j][r] + bv);
            }
        }
    }
}

// ---------------------------------------------------------------------------
// Attention: one block per (bh, 32-query tile). 4 waves. T=448, HD=64, H=16.
// ---------------------------------------------------------------------------
__global__ __launch_bounds__(256) void attn_kernel(
    const bf16* __restrict__ Q, int qstride,
    const bf16* __restrict__ Kp, int kstride,
    const bf16* __restrict__ Vp, int vstride,
    bf16* __restrict__ O, int causal) {
    const int T_ = 448, HD = 64, OC = 1024;
    const float scale = 0.03125f;  // C^-0.5 (full-embed scaling per reference)
    const int bh = blockIdx.y, b = bh >> 4, h = bh & 15;
    const int q0 = blockIdx.x * 32;
    const int tid = threadIdx.x, wave = tid >> 6, lane = tid & 63;
    const int quad = lane >> 4, l16 = lane & 15;

    __shared__ bf16 Pb[32][464];
    __shared__ bf16 VT[64][40];
    __shared__ float redp[32][4];
    __shared__ float Mbuf[32], Lbuf[32];

    const bf16* qb = Q + (size_t)(b * T_ + q0) * qstride + h * HD;
    const bf16* kb = Kp + (size_t)(b * T_) * kstride + h * HD;
    const bf16* vb = Vp + (size_t)(b * T_) * vstride + h * HD;

    bf16x8 qf[2][2];
#pragma unroll
    for (int qi = 0; qi < 2; qi++)
#pragma unroll
        for (int kh = 0; kh < 2; kh++)
            qf[qi][kh] = *(const bf16x8*)(qb + (size_t)(qi * 16 + l16) * qstride + kh * 32 + quad * 8);

    float S[2][7][4];
#pragma unroll
    for (int kt = 0; kt < 7; kt++) {
        const int s = wave * 112 + kt * 16 + l16;
        const bf16* kr = kb + (size_t)s * kstride + quad * 8;
        bf16x8 kf0 = *(const bf16x8*)kr;
        bf16x8 kf1 = *(const bf16x8*)(kr + 32);
#pragma unroll
        for (int qi = 0; qi < 2; qi++) {
            floatx4 c = {};
            c = mfma16(qf[qi][0], kf0, c);
            c = mfma16(qf[qi][1], kf1, c);
#pragma unroll
            for (int r = 0; r < 4; r++) {
                float v = c[r] * scale;
                if (causal) {
                    const int t = q0 + qi * 16 + quad * 4 + r;
                    if (s > t) v = -30000.0f;
                }
                S[qi][kt][r] = v;
            }
        }
    }

    float mx[2][4];
#pragma unroll
    for (int qi = 0; qi < 2; qi++)
#pragma unroll
        for (int r = 0; r < 4; r++) {
            float m = S[qi][0][r];
#pragma unroll
            for (int kt = 1; kt < 7; kt++) m = fmaxf(m, S[qi][kt][r]);
#pragma unroll
            for (int off = 1; off < 16; off <<= 1) m = fmaxf(m, __shfl_xor(m, off));
            mx[qi][r] = m;
        }
    if (l16 == 0) {
#pragma unroll
        for (int qi = 0; qi < 2; qi++)
#pragma unroll
            for (int r = 0; r < 4; r++) redp[qi * 16 + quad * 4 + r][wave] = mx[qi][r];
    }
    __syncthreads();
    if (tid < 32)
        Mbuf[tid] = fmaxf(fmaxf(redp[tid][0], redp[tid][1]),
                          fmaxf(redp[tid][2], redp[tid][3]));
    __syncthreads();

#pragma unroll
    for (int qi = 0; qi < 2; qi++)
#pragma unroll
        for (int r = 0; r < 4; r++) {
            const float Mv = Mbuf[qi * 16 + quad * 4 + r];
            float acc = 0.0f;
#pragma unroll
            for (int kt = 0; kt < 7; kt++) {
                const float p = __expf(fminf(S[qi][kt][r] - Mv, 0.0f));
                acc += p;
                Pb[qi * 16 + quad * 4 + r][wave * 112 + kt * 16 + l16] = (bf16)p;
            }
#pragma unroll
            for (int off = 1; off < 16; off <<= 1) acc += __shfl_xor(acc, off);
            if (l16 == 0) redp[qi * 16 + quad * 4 + r][wave] = acc;
        }
    __syncthreads();
    if (tid < 32)
        Lbuf[tid] = redp[tid][0] + redp[tid][1] + redp[tid][2] + redp[tid][3];

    floatx4 oacc[2] = {};
    const int qi3 = wave & 1, djb = (wave >> 1) * 2;
    for (int kt = 0; kt < 14; kt++) {
        const int s0 = kt * 32;
        const bf16* vsrc = vb + (size_t)(s0 + (tid & 31)) * vstride + (tid >> 5) * 8;
        bf16x8 vv = *(const bf16x8*)vsrc;
        __syncthreads();
#pragma unroll
        for (int e = 0; e < 8; e++) VT[(tid >> 5) * 8 + e][tid & 31] = vv[e];
        __syncthreads();
        bf16x8 pa = *(const bf16x8*)(&Pb[qi3 * 16 + l16][s0 + quad * 8]);
#pragma unroll
        for (int u = 0; u < 2; u++) {
            bf16x8 bv = *(const bf16x8*)(&VT[(djb + u) * 16 + l16][quad * 8]);
            oacc[u] = mfma16(pa, bv, oacc[u]);
        }
    }

#pragma unroll
    for (int u = 0; u < 2; u++) {
        const int d = (djb + u) * 16 + l16;
#pragma unroll
        for (int r = 0; r < 4; r++) {
            const int t = q0 + qi3 * 16 + quad * 4 + r;
            const float L = Lbuf[qi3 * 16 + quad * 4 + r];
            O[(size_t)(b * T_ + t) * OC + h * HD + d] = (bf16)(oacc[u][r] / L);
        }
    }
}

// ---------------------------------------------------------------------------
// Arena (~130.1 MB): W_T [0,32) | resf [32,60) | Cb/Hb [60,102/116) |
// Db [102,116) | x3b [116,130) | vecs+flag @130.
// ---------------------------------------------------------------------------
extern "C" void kernel_launch(void* const* d_in, const int* in_sizes, int n_in,
                              void* d_out, int out_size, void* d_ws, size_t ws_size,
                              hipStream_t stream) {
    const void* tgt_r  = d_in[0];
    const void* src_r  = d_in[1];
    const void* wqkv_r = d_in[2];
    const void* wpr_r  = d_in[3];
    const void* bpr_r  = d_in[4];
    const void* wkv_r  = d_in[5];
    const void* wq_r   = d_in[6];
    const void* wep_r  = d_in[7];
    const void* bep_r  = d_in[8];
    const void* fw1_r  = d_in[9];
    const void* fb1_r  = d_in[10];
    const void* fw2_r  = d_in[11];
    const void* fb2_r  = d_in[12];
    const void* l1g_r  = d_in[13];
    const void* l1b_r  = d_in[14];
    const void* l2g_r  = d_in[15];
    const void* l2b_r  = d_in[16];
    const void* l3g_r  = d_in[17];
    const void* l3b_r  = d_in[18];

    const size_t MB = 1u << 20;
    char* base = (char*)d_ws;
    bf16*  WT   = (bf16*)(base + 0 * MB);
    float* resf = (float*)(base + 32 * MB);
    bf16*  Cb   = (bf16*)(base + 60 * MB);
    bf16*  Hb   = Cb;
    bf16*  Db   = (bf16*)(base + 102 * MB);
    bf16*  x3b  = (bf16*)(base + 116 * MB);
    bf16*  vecs = (bf16*)(base + 130 * MB);
    int*   flag = (int*)(base + 130 * MB + 65536);
    bf16*  kvb  = Cb + (size_t)7168 * 1024;

    bf16* T_qkv = WT + 0;
    bf16* T_pr  = WT + 3145728;
    bf16* T_kv  = WT + 4194304;
    bf16* T_q   = WT + 6291456;
    bf16* T_ep  = WT + 7340032;
    bf16* T_f1  = WT + 8388608;
    bf16* T_f2  = WT + 12582912;

    bf16* v_bpr = vecs + 0;
    bf16* v_bep = vecs + 1024;
    bf16* v_fb1 = vecs + 2048;
    bf16* v_fb2 = vecs + 6144;
    bf16 *v_l1g = vecs + 7168,  *v_l1b = vecs + 8192;
    bf16 *v_l2g = vecs + 9216,  *v_l2b = vecs + 10240;
    bf16 *v_l3g = vecs + 11264, *v_l3b = vecs + 12288;

    const int M = 7168;
    dim3 blk(256);
    dim3 tb(32, 8);

    // 0. dtype detection, vec conversion, all weight transposes
    detect_dtype<<<1, blk, 0, stream>>>((const bf16*)tgt_r, flag);
    convert_vecs<<<52, blk, 0, stream>>>(bpr_r, bep_r, fb1_r, fb2_r, l1g_r, l1b_r,
                                         l2g_r, l2b_r, l3g_r, l3b_r, vecs, flag);
    transpose_all<<<16384, tb, 0, stream>>>(wqkv_r, wpr_r, wkv_r, wq_r, wep_r,
                                            fw1_r, fw2_r, WT, flag);

    // 1. x1 = LN1(tgt)
    ln_dyn<<<M, blk, 0, stream>>>(tgt_r, v_l1g, v_l1b, Db, flag);
    // 2. qkv = x1 @ wqkv
    gemm_bt<<<24 * 56, blk, 0, stream>>>(
        Db, 1024, T_qkv, 1024, nullptr, nullptr, nullptr, Cb, nullptr, nullptr,
        flag, M, 3072, 1024, 0);
    // 3. self-attn (causal)
    attn_kernel<<<dim3(14, 256), blk, 0, stream>>>(Cb, 3072, Cb + 1024, 3072, Cb + 2048, 3072, Db, 1);
    // 4. resf = tgt + bpr, then += attn1 @ wproj (split-K x2)
    resf_init<<<7168, blk, 0, stream>>>(tgt_r, v_bpr, resf, flag);
    gemm_splitk<<<2 * 8 * 56, blk, 0, stream>>>(
        Db, 1024, T_pr, 1024, nullptr, resf, M, 1024, 512);
    // 5. xq = LN2(resf)
    ln_f32<<<M, blk, 0, stream>>>(resf, v_l2g, v_l2b, Db);
    // 6. xs = LN2(src)
    ln_dyn<<<M, blk, 0, stream>>>(src_r, v_l2g, v_l2b, Cb, flag);
    // 7. kv = xs @ wkv
    gemm_bt<<<16 * 56, blk, 0, stream>>>(
        Cb, 1024, T_kv, 1024, nullptr, nullptr, nullptr, kvb, nullptr, nullptr,
        flag, M, 2048, 1024, 0);
    // 8. q2 = xq @ wq
    gemm_bt<<<8 * 56, blk, 0, stream>>>(
        Db, 1024, T_q, 1024, nullptr, nullptr, nullptr, Cb, nullptr, nullptr,
        flag, M, 1024, 1024, 0);
    // 9. cross-attn
    attn_kernel<<<dim3(14, 256), blk, 0, stream>>>(Cb, 1024, kvb, 2048, kvb + 1024, 2048, Db, 0);
    // 10. resf += attn2 @ wedproj + bep (split-K x2, bias on split 0)
    gemm_splitk<<<2 * 8 * 56, blk, 0, stream>>>(
        Db, 1024, T_ep, 1024, v_bep, resf, M, 1024, 512);
    // 11. x3 = LN3(tgt)
    ln_dyn<<<M, blk, 0, stream>>>(tgt_r, v_l3g, v_l3b, x3b, flag);
    // 12. h = relu(x3 @ fw1 + fb1)
    gemm_bt<<<32 * 56, blk, 0, stream>>>(
        x3b, 1024, T_f1, 1024, v_fb1, nullptr, nullptr, Hb, nullptr, nullptr,
        flag, M, 4096, 1024, 1);
    // 13. resf += h @ fw2 (split-K x4), then d_out = resf + fb2
    gemm_splitk<<<4 * 8 * 56, blk, 0, stream>>>(
        Hb, 4096, T_f2, 4096, nullptr, resf, M, 1024, 1024);
    out_final<<<7168, blk, 0, stream>>>(resf, v_fb2, d_out, flag);
}

// Round 7
// 815.427 us; speedup vs baseline: 1.1382x; 1.1382x over previous
//
#include <hip/hip_runtime.h>

typedef __bf16 bf16;
typedef __bf16 bf16x8 __attribute__((ext_vector_type(8)));
typedef float floatx4 __attribute__((ext_vector_type(4)));

__device__ __forceinline__ floatx4 mfma16(bf16x8 a, bf16x8 b, floatx4 c) {
    return __builtin_amdgcn_mfma_f32_16x16x32_bf16(a, b, c, 0, 0, 0);
}

__device__ __forceinline__ void load16_lds(const void* g, void* l) {
    __builtin_amdgcn_global_load_lds(
        (const __attribute__((address_space(1))) void*)g,
        (__attribute__((address_space(3))) void*)(unsigned int)(unsigned long long)l,
        16, 0, 0);
}

// ---------------------------------------------------------------------------
// Dtype detector: fp32 buffers viewed as bf16 show wild exponents -> flag=1.
// ---------------------------------------------------------------------------
__global__ __launch_bounds__(256) void detect_dtype(const bf16* __restrict__ p,
                                                    int* __restrict__ flag) {
    __shared__ int bad;
    if (threadIdx.x == 0) bad = 0;
    __syncthreads();
    int lbad = 0;
    for (int i = threadIdx.x; i < 4096; i += 256) {
        const float v = (float)p[i];
        if (!isfinite(v) || fabsf(v) > 1e10f) lbad = 1;
    }
    if (lbad) atomicOr(&bad, 1);
    __syncthreads();
    if (threadIdx.x == 0) *flag = bad;
}

// ---------------------------------------------------------------------------
// Small vectors -> bf16 arena. bpr@0 bep@1024 fb1@2048(4096) fb2@6144
// l1g@7168 l1b@8192 l2g@9216 l2b@10240 l3g@11264 l3b@12288. 13312 total.
// ---------------------------------------------------------------------------
__global__ __launch_bounds__(256) void convert_vecs(
    const void* bpr, const void* bep, const void* fb1, const void* fb2,
    const void* g1, const void* b1, const void* g2, const void* b2,
    const void* g3, const void* b3, bf16* __restrict__ out,
    const int* __restrict__ flagp) {
    const int fl = *flagp;
    const int idx = blockIdx.x * 256 + threadIdx.x;
    const void* src;
    int off;
    if (idx < 1024)      { src = bpr; off = idx; }
    else if (idx < 2048) { src = bep; off = idx - 1024; }
    else if (idx < 6144) { src = fb1; off = idx - 2048; }
    else if (idx < 7168) { src = fb2; off = idx - 6144; }
    else {
        const void* t[6] = {g1, b1, g2, b2, g3, b3};
        src = t[(idx - 7168) >> 10];
        off = idx & 1023;
    }
    out[idx] = fl ? (bf16)((const float*)src)[off] : ((const bf16*)src)[off];
}

// ---------------------------------------------------------------------------
// LayerNorm, fp32 input (for resf).
// ---------------------------------------------------------------------------
__global__ __launch_bounds__(256) void ln_f32(const float* __restrict__ X,
                                              const bf16* __restrict__ G,
                                              const bf16* __restrict__ Bv,
                                              bf16* __restrict__ Y) {
    const int row = blockIdx.x;
    const int tid = threadIdx.x;
    const float* x = X + (size_t)row * 1024 + tid * 4;
    float v[4];
#pragma unroll
    for (int i = 0; i < 4; i++) v[i] = x[i];
    float s = v[0] + v[1] + v[2] + v[3];
    float q = v[0] * v[0] + v[1] * v[1] + v[2] * v[2] + v[3] * v[3];
#pragma unroll
    for (int off = 32; off >= 1; off >>= 1) {
        s += __shfl_xor(s, off);
        q += __shfl_xor(q, off);
    }
    __shared__ float ss[4], qq[4];
    const int wave = tid >> 6, lane = tid & 63;
    if (lane == 0) { ss[wave] = s; qq[wave] = q; }
    __syncthreads();
    s = ss[0] + ss[1] + ss[2] + ss[3];
    q = qq[0] + qq[1] + qq[2] + qq[3];
    const float mu = s * (1.0f / 1024.0f);
    const float var = q * (1.0f / 1024.0f) - mu * mu;
    const float rs = rsqrtf(var + 1e-5f);
    bf16* y = Y + (size_t)row * 1024 + tid * 4;
    const bf16* g = G + tid * 4;
    const bf16* b = Bv + tid * 4;
#pragma unroll
    for (int i = 0; i < 4; i++)
        y[i] = (bf16)((v[i] - mu) * rs * (float)g[i] + (float)b[i]);
}

// ---------------------------------------------------------------------------
// LayerNorm, raw input with device-side dtype dispatch (fp32/bf16 per flag).
// ---------------------------------------------------------------------------
__global__ __launch_bounds__(256) void ln_dyn(const void* __restrict__ X,
                                              const bf16* __restrict__ G,
                                              const bf16* __restrict__ Bv,
                                              bf16* __restrict__ Y,
                                              const int* __restrict__ flagp) {
    const int fl = *flagp;
    const int row = blockIdx.x;
    const int tid = threadIdx.x;
    float v[4];
    if (fl) {
        const float* x = (const float*)X + (size_t)row * 1024 + tid * 4;
#pragma unroll
        for (int i = 0; i < 4; i++) v[i] = x[i];
    } else {
        const bf16* x = (const bf16*)X + (size_t)row * 1024 + tid * 4;
#pragma unroll
        for (int i = 0; i < 4; i++) v[i] = (float)x[i];
    }
    float s = v[0] + v[1] + v[2] + v[3];
    float q = v[0] * v[0] + v[1] * v[1] + v[2] * v[2] + v[3] * v[3];
#pragma unroll
    for (int off = 32; off >= 1; off >>= 1) {
        s += __shfl_xor(s, off);
        q += __shfl_xor(q, off);
    }
    __shared__ float ss[4], qq[4];
    const int wave = tid >> 6, lane = tid & 63;
    if (lane == 0) { ss[wave] = s; qq[wave] = q; }
    __syncthreads();
    s = ss[0] + ss[1] + ss[2] + ss[3];
    q = qq[0] + qq[1] + qq[2] + qq[3];
    const float mu = s * (1.0f / 1024.0f);
    const float var = q * (1.0f / 1024.0f) - mu * mu;
    const float rs = rsqrtf(var + 1e-5f);
    bf16* y = Y + (size_t)row * 1024 + tid * 4;
    const bf16* g = G + tid * 4;
    const bf16* b = Bv + tid * 4;
#pragma unroll
    for (int i = 0; i < 4; i++)
        y[i] = (bf16)((v[i] - mu) * rs * (float)g[i] + (float)b[i]);
}

// ---------------------------------------------------------------------------
// One-shot transpose+convert of ALL 7 weights into the W_T arena.
// ---------------------------------------------------------------------------
__global__ __launch_bounds__(256) void transpose_all(
    const void* w0, const void* w1, const void* w2, const void* w3,
    const void* w4, const void* w5, const void* w6,
    bf16* __restrict__ out_base, const int* __restrict__ flagp) {
    const int fl = *flagp;
    const int cum[8] = {0, 3072, 4096, 6144, 7168, 8192, 12288, 16384};
    const int ntv[7] = {96, 32, 64, 32, 32, 128, 32};
    const int ldi[7] = {3072, 1024, 2048, 1024, 1024, 4096, 1024};
    const int ldo[7] = {1024, 1024, 1024, 1024, 1024, 1024, 4096};
    const size_t ooff[7] = {0, 3145728, 4194304, 6291456, 7340032, 8388608, 12582912};
    const void* ws[7] = {w0, w1, w2, w3, w4, w5, w6};

    const int g = blockIdx.x;
    int w = 0;
#pragma unroll
    for (int i = 1; i < 7; i++) if (g >= cum[i]) w = i;
    const int t = g - cum[w];
    const int xt = t % ntv[w], yt = t / ntv[w];
    const int n0 = xt * 32, k0 = yt * 32;
    const void* in = ws[w];
    bf16* out = out_base + ooff[w];
    const int ldin = ldi[w], ldout = ldo[w];

    __shared__ bf16 tile[32][33];
    const int x = threadIdx.x, y = threadIdx.y;
#pragma unroll
    for (int i = 0; i < 4; i++) {
        const size_t idx = (size_t)(k0 + y + 8 * i) * ldin + n0 + x;
        tile[y + 8 * i][x] = fl ? (bf16)((const float*)in)[idx]
                                : ((const bf16*)in)[idx];
    }
    __syncthreads();
#pragma unroll
    for (int i = 0; i < 4; i++)
        out[(size_t)(n0 + y + 8 * i) * ldout + k0 + x] = tile[x][y + 8 * i];
}

// ---------------------------------------------------------------------------
// GEMM: C[M,N] = A @ B^T'. Tile 128 x TN (TN = 128 or 64), BK=32, async
// staging, XCD swizzle (yb = g%56 keeps A-strip blocks on one XCD).
// TN=64 doubles the grid for skinny-N GEMMs -> more resident blocks/CU to
// hide the vmcnt(0)+barrier drain (round-5 FFN2 was block-starved at 1.75/CU).
// Epilogue: +bias, relu, +resd (raw dtype), +resf, out f32/bf16/dual.
// ---------------------------------------------------------------------------
template <int TN>
__global__ __launch_bounds__(256) void gemm_bt(
    const bf16* __restrict__ A, int lda,
    const bf16* __restrict__ Bt, int ldb,
    const bf16* __restrict__ bias,
    const void* resd,
    const float* resf,
    bf16* outb, float* outf, void* dual,
    const int* __restrict__ flagp,
    int M, int N, int K, int relu) {
    constexpr int NJ = TN / 32;          // MFMA col-tiles per wave: 4 or 2
    __shared__ bf16 As[128 * 32];
    __shared__ bf16 Bs[TN * 32];
    const int fl = *flagp;
    const int tid = threadIdx.x;
    const int wave = tid >> 6, lane = tid & 63;
    const int quad = lane >> 4, l16 = lane & 15;
    const int g = blockIdx.x;
    const int yb = g % 56, xb = g / 56;
    const int m0 = yb * 128, n0 = xb * TN;
    const int wm = (wave >> 1) * 64, wn = (wave & 1) * (TN / 2);
    const int srow = tid >> 2, scol = (tid & 3) * 8;

    floatx4 acc[4][NJ] = {};

    const bf16* gA = A + (size_t)(m0 + srow) * lda + scol;
    const bf16* gB = Bt + (size_t)(n0 + srow) * ldb + scol;
    const size_t a64 = (size_t)64 * lda, b64 = (size_t)64 * ldb;

    for (int k0 = 0; k0 < K; k0 += 32) {
        load16_lds(gA + k0, &As[tid * 8]);
        load16_lds(gA + k0 + a64, &As[(tid + 256) * 8]);
        load16_lds(gB + k0, &Bs[tid * 8]);
        if (TN == 128) load16_lds(gB + k0 + b64, &Bs[(tid + 256) * 8]);
        __syncthreads();
        bf16x8 af[4], bfr[NJ];
#pragma unroll
        for (int i = 0; i < 4; i++)
            af[i] = *(const bf16x8*)(&As[(wm + i * 16 + l16) * 32 + quad * 8]);
#pragma unroll
        for (int j = 0; j < NJ; j++)
            bfr[j] = *(const bf16x8*)(&Bs[(wn + j * 16 + l16) * 32 + quad * 8]);
#pragma unroll
        for (int i = 0; i < 4; i++)
#pragma unroll
            for (int j = 0; j < NJ; j++)
                acc[i][j] = mfma16(af[i], bfr[j], acc[i][j]);
        __syncthreads();
    }

#pragma unroll
    for (int i = 0; i < 4; i++) {
        const int mbase = m0 + wm + i * 16 + quad * 4;
#pragma unroll
        for (int j = 0; j < NJ; j++) {
            const int n = n0 + wn + j * 16 + l16;
            const float bv = bias ? (float)bias[n] : 0.0f;
#pragma unroll
            for (int r = 0; r < 4; r++) {
                const size_t idx = (size_t)(mbase + r) * N + n;
                float v = acc[i][j][r] + bv;
                if (relu && v < 0.0f) v = 0.0f;
                if (resd) v += fl ? ((const float*)resd)[idx]
                                  : (float)((const bf16*)resd)[idx];
                if (resf) v += resf[idx];
                if (dual) {
                    if (fl) ((float*)dual)[idx] = v;
                    else ((bf16*)dual)[idx] = (bf16)v;
                } else if (outf) {
                    outf[idx] = v;
                } else {
                    outb[idx] = (bf16)v;
                }
            }
        }
    }
}

// ---------------------------------------------------------------------------
// Attention: one block per (bh, 32-query tile). 4 waves. T=448, HD=64, H=16.
// ---------------------------------------------------------------------------
__global__ __launch_bounds__(256) void attn_kernel(
    const bf16* __restrict__ Q, int qstride,
    const bf16* __restrict__ Kp, int kstride,
    const bf16* __restrict__ Vp, int vstride,
    bf16* __restrict__ O, int causal) {
    const int T_ = 448, HD = 64, OC = 1024;
    const float scale = 0.03125f;  // C^-0.5 (full-embed scaling per reference)
    const int bh = blockIdx.y, b = bh >> 4, h = bh & 15;
    const int q0 = blockIdx.x * 32;
    const int tid = threadIdx.x, wave = tid >> 6, lane = tid & 63;
    const int quad = lane >> 4, l16 = lane & 15;

    __shared__ bf16 Pb[32][464];
    __shared__ bf16 VT[64][40];
    __shared__ float redp[32][4];
    __shared__ float Mbuf[32], Lbuf[32];

    const bf16* qb = Q + (size_t)(b * T_ + q0) * qstride + h * HD;
    const bf16* kb = Kp + (size_t)(b * T_) * kstride + h * HD;
    const bf16* vb = Vp + (size_t)(b * T_) * vstride + h * HD;

    bf16x8 qf[2][2];
#pragma unroll
    for (int qi = 0; qi < 2; qi++)
#pragma unroll
        for (int kh = 0; kh < 2; kh++)
            qf[qi][kh] = *(const bf16x8*)(qb + (size_t)(qi * 16 + l16) * qstride + kh * 32 + quad * 8);

    float S[2][7][4];
#pragma unroll
    for (int kt = 0; kt < 7; kt++) {
        const int s = wave * 112 + kt * 16 + l16;
        const bf16* kr = kb + (size_t)s * kstride + quad * 8;
        bf16x8 kf0 = *(const bf16x8*)kr;
        bf16x8 kf1 = *(const bf16x8*)(kr + 32);
#pragma unroll
        for (int qi = 0; qi < 2; qi++) {
            floatx4 c = {};
            c = mfma16(qf[qi][0], kf0, c);
            c = mfma16(qf[qi][1], kf1, c);
#pragma unroll
            for (int r = 0; r < 4; r++) {
                float v = c[r] * scale;
                if (causal) {
                    const int t = q0 + qi * 16 + quad * 4 + r;
                    if (s > t) v = -30000.0f;
                }
                S[qi][kt][r] = v;
            }
        }
    }

    float mx[2][4];
#pragma unroll
    for (int qi = 0; qi < 2; qi++)
#pragma unroll
        for (int r = 0; r < 4; r++) {
            float m = S[qi][0][r];
#pragma unroll
            for (int kt = 1; kt < 7; kt++) m = fmaxf(m, S[qi][kt][r]);
#pragma unroll
            for (int off = 1; off < 16; off <<= 1) m = fmaxf(m, __shfl_xor(m, off));
            mx[qi][r] = m;
        }
    if (l16 == 0) {
#pragma unroll
        for (int qi = 0; qi < 2; qi++)
#pragma unroll
            for (int r = 0; r < 4; r++) redp[qi * 16 + quad * 4 + r][wave] = mx[qi][r];
    }
    __syncthreads();
    if (tid < 32)
        Mbuf[tid] = fmaxf(fmaxf(redp[tid][0], redp[tid][1]),
                          fmaxf(redp[tid][2], redp[tid][3]));
    __syncthreads();

#pragma unroll
    for (int qi = 0; qi < 2; qi++)
#pragma unroll
        for (int r = 0; r < 4; r++) {
            const float Mv = Mbuf[qi * 16 + quad * 4 + r];
            float acc = 0.0f;
#pragma unroll
            for (int kt = 0; kt < 7; kt++) {
                const float p = __expf(fminf(S[qi][kt][r] - Mv, 0.0f));
                acc += p;
                Pb[qi * 16 + quad * 4 + r][wave * 112 + kt * 16 + l16] = (bf16)p;
            }
#pragma unroll
            for (int off = 1; off < 16; off <<= 1) acc += __shfl_xor(acc, off);
            if (l16 == 0) redp[qi * 16 + quad * 4 + r][wave] = acc;
        }
    __syncthreads();
    if (tid < 32)
        Lbuf[tid] = redp[tid][0] + redp[tid][1] + redp[tid][2] + redp[tid][3];

    floatx4 oacc[2] = {};
    const int qi3 = wave & 1, djb = (wave >> 1) * 2;
    for (int kt = 0; kt < 14; kt++) {
        const int s0 = kt * 32;
        const bf16* vsrc = vb + (size_t)(s0 + (tid & 31)) * vstride + (tid >> 5) * 8;
        bf16x8 vv = *(const bf16x8*)vsrc;
        __syncthreads();
#pragma unroll
        for (int e = 0; e < 8; e++) VT[(tid >> 5) * 8 + e][tid & 31] = vv[e];
        __syncthreads();
        bf16x8 pa = *(const bf16x8*)(&Pb[qi3 * 16 + l16][s0 + quad * 8]);
#pragma unroll
        for (int u = 0; u < 2; u++) {
            bf16x8 bv = *(const bf16x8*)(&VT[(djb + u) * 16 + l16][quad * 8]);
            oacc[u] = mfma16(pa, bv, oacc[u]);
        }
    }

#pragma unroll
    for (int u = 0; u < 2; u++) {
        const int d = (djb + u) * 16 + l16;
#pragma unroll
        for (int r = 0; r < 4; r++) {
            const int t = q0 + qi3 * 16 + quad * 4 + r;
            const float L = Lbuf[qi3 * 16 + quad * 4 + r];
            O[(size_t)(b * T_ + t) * OC + h * HD + d] = (bf16)(oacc[u][r] / L);
        }
    }
}

// ---------------------------------------------------------------------------
// Arena (~130.1 MB): W_T [0,32) | resf [32,60) | Cb/Hb [60,102/116) |
// Db [102,116) | x3b [116,130) | vecs+flag @130.
// ---------------------------------------------------------------------------
extern "C" void kernel_launch(void* const* d_in, const int* in_sizes, int n_in,
                              void* d_out, int out_size, void* d_ws, size_t ws_size,
                              hipStream_t stream) {
    const void* tgt_r  = d_in[0];
    const void* src_r  = d_in[1];
    const void* wqkv_r = d_in[2];
    const void* wpr_r  = d_in[3];
    const void* bpr_r  = d_in[4];
    const void* wkv_r  = d_in[5];
    const void* wq_r   = d_in[6];
    const void* wep_r  = d_in[7];
    const void* bep_r  = d_in[8];
    const void* fw1_r  = d_in[9];
    const void* fb1_r  = d_in[10];
    const void* fw2_r  = d_in[11];
    const void* fb2_r  = d_in[12];
    const void* l1g_r  = d_in[13];
    const void* l1b_r  = d_in[14];
    const void* l2g_r  = d_in[15];
    const void* l2b_r  = d_in[16];
    const void* l3g_r  = d_in[17];
    const void* l3b_r  = d_in[18];

    const size_t MB = 1u << 20;
    char* base = (char*)d_ws;
    bf16*  WT   = (bf16*)(base + 0 * MB);
    float* resf = (float*)(base + 32 * MB);
    bf16*  Cb   = (bf16*)(base + 60 * MB);
    bf16*  Hb   = Cb;
    bf16*  Db   = (bf16*)(base + 102 * MB);
    bf16*  x3b  = (bf16*)(base + 116 * MB);
    bf16*  vecs = (bf16*)(base + 130 * MB);
    int*   flag = (int*)(base + 130 * MB + 65536);
    bf16*  kvb  = Cb + (size_t)7168 * 1024;

    bf16* T_qkv = WT + 0;
    bf16* T_pr  = WT + 3145728;
    bf16* T_kv  = WT + 4194304;
    bf16* T_q   = WT + 6291456;
    bf16* T_ep  = WT + 7340032;
    bf16* T_f1  = WT + 8388608;
    bf16* T_f2  = WT + 12582912;

    bf16* v_bpr = vecs + 0;
    bf16* v_bep = vecs + 1024;
    bf16* v_fb1 = vecs + 2048;
    bf16* v_fb2 = vecs + 6144;
    bf16 *v_l1g = vecs + 7168,  *v_l1b = vecs + 8192;
    bf16 *v_l2g = vecs + 9216,  *v_l2b = vecs + 10240;
    bf16 *v_l3g = vecs + 11264, *v_l3b = vecs + 12288;

    const int M = 7168;
    dim3 blk(256);
    dim3 tb(32, 8);

    // 0. dtype detection, vec conversion, all weight transposes
    detect_dtype<<<1, blk, 0, stream>>>((const bf16*)tgt_r, flag);
    convert_vecs<<<52, blk, 0, stream>>>(bpr_r, bep_r, fb1_r, fb2_r, l1g_r, l1b_r,
                                         l2g_r, l2b_r, l3g_r, l3b_r, vecs, flag);
    transpose_all<<<16384, tb, 0, stream>>>(wqkv_r, wpr_r, wkv_r, wq_r, wep_r,
                                            fw1_r, fw2_r, WT, flag);

    // 1. x1 = LN1(tgt)
    ln_dyn<<<M, blk, 0, stream>>>(tgt_r, v_l1g, v_l1b, Db, flag);
    // 2. qkv = x1 @ wqkv  (N=3072, 1344 blocks)
    gemm_bt<128><<<24 * 56, blk, 0, stream>>>(
        Db, 1024, T_qkv, 1024, nullptr, nullptr, nullptr, Cb, nullptr, nullptr,
        flag, M, 3072, 1024, 0);
    // 3. self-attn (causal)
    attn_kernel<<<dim3(14, 256), blk, 0, stream>>>(Cb, 3072, Cb + 1024, 3072, Cb + 2048, 3072, Db, 1);
    // 4. resf = attn1 @ wproj + bpr + tgt  (N=1024 -> TN=64, 896 blocks)
    gemm_bt<64><<<16 * 56, blk, 0, stream>>>(
        Db, 1024, T_pr, 1024, v_bpr, tgt_r, nullptr, nullptr, resf, nullptr,
        flag, M, 1024, 1024, 0);
    // 5. xq = LN2(resf)
    ln_f32<<<M, blk, 0, stream>>>(resf, v_l2g, v_l2b, Db);
    // 6. xs = LN2(src)
    ln_dyn<<<M, blk, 0, stream>>>(src_r, v_l2g, v_l2b, Cb, flag);
    // 7. kv = xs @ wkv  (N=2048, 896 blocks)
    gemm_bt<128><<<16 * 56, blk, 0, stream>>>(
        Cb, 1024, T_kv, 1024, nullptr, nullptr, nullptr, kvb, nullptr, nullptr,
        flag, M, 2048, 1024, 0);
    // 8. q2 = xq @ wq  (TN=64, 896 blocks)
    gemm_bt<64><<<16 * 56, blk, 0, stream>>>(
        Db, 1024, T_q, 1024, nullptr, nullptr, nullptr, Cb, nullptr, nullptr,
        flag, M, 1024, 1024, 0);
    // 9. cross-attn
    attn_kernel<<<dim3(14, 256), blk, 0, stream>>>(Cb, 1024, kvb, 2048, kvb + 1024, 2048, Db, 0);
    // 10. resf += attn2 @ wedproj + bep  (TN=64, 896 blocks, in-place)
    gemm_bt<64><<<16 * 56, blk, 0, stream>>>(
        Db, 1024, T_ep, 1024, v_bep, nullptr, resf, nullptr, resf, nullptr,
        flag, M, 1024, 1024, 0);
    // 11. x3 = LN3(tgt)
    ln_dyn<<<M, blk, 0, stream>>>(tgt_r, v_l3g, v_l3b, x3b, flag);
    // 12. h = relu(x3 @ fw1 + fb1)  (N=4096, 1792 blocks)
    gemm_bt<128><<<32 * 56, blk, 0, stream>>>(
        x3b, 1024, T_f1, 1024, v_fb1, nullptr, nullptr, Hb, nullptr, nullptr,
        flag, M, 4096, 1024, 1);
    // 13. out = h @ fw2 + fb2 + resf -> d_out  (K=4096, TN=64, 896 blocks)
    gemm_bt<64><<<16 * 56, blk, 0, stream>>>(
        Hb, 4096, T_f2, 4096, v_fb2, nullptr, resf, nullptr, nullptr, d_out,
        flag, M, 1024, 4096, 0);
}